// Round 13
// baseline (191.383 us; speedup 1.0000x reference)
//
#include <hip/hip_runtime.h>
#include <hip/hip_bf16.h>
#include <math.h>

// Problem constants
#define BATCH 2
#define SEQ   2048
#define DIM   1024
#define HEADS 16
#define DH    64
#define MROWS (BATCH*SEQ)      // 4096
#define NTOT  3072             // gemm output cols: q(1024) | k(1024) | v(1024)
#define KDIM  1024

typedef float f32x4 __attribute__((ext_vector_type(4)));
typedef __bf16 bf16x8 __attribute__((ext_vector_type(8)));
typedef __bf16 bf16x4 __attribute__((ext_vector_type(4)));

// Fragment-order buffers (1KB block = 64 lanes x 16B chunk, lane ln = featquad*16 + (token&15)):
//  qF/kF: block index ((b*128 + g)*16 + h)*2 + kf      g = token-group (16 tokens)
//  vF   : block index ((bh*32 + kvt)*4 + nb)*2 + kf    kvt = kv/64, dv-group nb
// Attn reads each block as  base + ln*16B  -> perfectly coalesced b128 loads.

__device__ __forceinline__ void gload_lds16(const void* g, void* l) {
    __builtin_amdgcn_global_load_lds((__attribute__((address_space(1))) void*)g,
                                     (__attribute__((address_space(3))) void*)l,
                                     16, 0, 0);
}

// ---------------------------------------------- prep: cast x -> bf16  +  transpose W -> Wt
__global__ void prep_kernel(const float* __restrict__ x,
                            const float* __restrict__ Wqk, const float* __restrict__ Wv,
                            __bf16* __restrict__ xb, __bf16* __restrict__ Wt) {
    __shared__ float T[64*65];
    const int bx = blockIdx.x;
    const int tid = threadIdx.x;
    if (bx < 4096) {
        int i = bx * 256 + tid;                   // 1M float4 = 4M floats exactly
        float4 f = ((const float4*)x)[i];
        bf16x4 o;
        o.x = (__bf16)f.x; o.y = (__bf16)f.y; o.z = (__bf16)f.z; o.w = (__bf16)f.w;
        ((bf16x4*)xb)[i] = o;
    } else {
        const int t = bx - 4096;                  // 0..767
        const int n0 = (t % 48) * 64;
        const int k0 = (t / 48) * 64;
#pragma unroll
        for (int i = 0; i < 16; ++i) {
            int idx = i*256 + tid;
            int kk = idx >> 6, nn = idx & 63;
            int n = n0 + nn;
            float v = (n < 2048) ? Wqk[(size_t)(k0+kk)*2048 + n]
                                 : Wv [(size_t)(k0+kk)*1024 + (n - 2048)];
            T[kk*65 + nn] = v;
        }
        __syncthreads();
#pragma unroll
        for (int i = 0; i < 16; ++i) {
            int idx = i*256 + tid;
            int nn = idx >> 6, kk = idx & 63;
            Wt[(size_t)(n0+nn)*KDIM + k0 + kk] = (__bf16)T[kk*65 + nn];
        }
    }
}

// ---------------------------------------------------------------- GEMM v6 (r11, unchanged)
#define BM 128
#define BN 128
#define BK 64

__global__ __launch_bounds__(256) void gemm_qkv_kernel(const __bf16* __restrict__ A,
                                                       const __bf16* __restrict__ Bt,
                                                       const float* __restrict__ bqk,
                                                       const float* __restrict__ bv,
                                                       __bf16* __restrict__ qF,
                                                       __bf16* __restrict__ kF,
                                                       __bf16* __restrict__ vF) {
    __shared__ alignas(16) __bf16 As[BM*BK];
    __shared__ alignas(16) __bf16 Bs[BN*BK];
    const int tid = threadIdx.x;
    const int wv = tid >> 6, ln = tid & 63;
    const int quad = ln >> 4, lm = ln & 15;
    const int m0 = blockIdx.y * BM, n0 = blockIdx.x * BN;
    const int wm = (wv >> 1) * 64, wn = (wv & 1) * 64;
    const int sw = lm & 7;

    f32x4 acc[4][4] = {};

    if (n0 < 2048) {
        // ---------------- q/k path: acc[nt][mt] = C^T tiles ----------------
        for (int kt = 0; kt < KDIM/BK; ++kt) {
            const int k0 = kt * BK;
            __syncthreads();
#pragma unroll
            for (int i = 0; i < 4; ++i) {
                int slot = wv*256 + i*64 + ln;
                int row = slot >> 3, p = slot & 7;
                int cc = (p ^ (row & 7)) * 8;
                gload_lds16(A  + (size_t)(m0 + row)*KDIM + k0 + cc, &As[(wv*256 + i*64)*8]);
                gload_lds16(Bt + (size_t)(n0 + row)*KDIM + k0 + cc, &Bs[(wv*256 + i*64)*8]);
            }
            __syncthreads();
#pragma unroll
            for (int kf = 0; kf < 2; ++kf) {
                bf16x8 af[4], bfr[4];
#pragma unroll
                for (int mt = 0; mt < 4; ++mt)
                    af[mt] = *(const bf16x8*)&As[(wm + mt*16 + lm)*BK + (((kf<<2)|quad) ^ sw)*8];
#pragma unroll
                for (int nt = 0; nt < 4; ++nt)
                    bfr[nt] = *(const bf16x8*)&Bs[(wn + nt*16 + lm)*BK + (((kf<<2)|quad) ^ sw)*8];
#pragma unroll
                for (int nt = 0; nt < 4; ++nt)
#pragma unroll
                    for (int mt = 0; mt < 4; ++mt)
                        acc[nt][mt] = __builtin_amdgcn_mfma_f32_16x16x32_bf16(bfr[nt], af[mt], acc[nt][mt], 0, 0, 0);
            }
        }
        __bf16* dst = (n0 < 1024) ? qF : kF;        // block-uniform
#pragma unroll
        for (int nt = 0; nt < 4; ++nt) {
            int f = n0 + wn + nt*16 + quad*4;
            float4 bs4 = *(const float4*)&bqk[f];
            int fl = f & 1023;
            int h  = fl >> 6;
            int ff = fl & 63;
            int fquad = (ff >> 3) & 3;
            int j0 = ff & 7;
            int kf = ff >> 5;
#pragma unroll
            for (int mt = 0; mt < 4; ++mt) {
                int m = m0 + wm + mt*16 + lm;
                int b = m >> 11, g = (m & 2047) >> 4;
                bf16x4 pk;
                pk[0] = (__bf16)(acc[nt][mt][0] + bs4.x);
                pk[1] = (__bf16)(acc[nt][mt][1] + bs4.y);
                pk[2] = (__bf16)(acc[nt][mt][2] + bs4.z);
                pk[3] = (__bf16)(acc[nt][mt][3] + bs4.w);
                size_t blk = (((size_t)(b*128 + g)*16 + h)*2 + kf);
                *(bf16x4*)&dst[blk*512 + (fquad*16 + lm)*8 + j0] = pk;
            }
        }
    } else {
        // ---------------- v path: acc[mt][nt] = C tiles -> vF frag-order ----------------
        for (int kt = 0; kt < KDIM/BK; ++kt) {
            const int k0 = kt * BK;
            __syncthreads();
#pragma unroll
            for (int i = 0; i < 4; ++i) {
                int slot = wv*256 + i*64 + ln;
                int row = slot >> 3, p = slot & 7;
                int cc = (p ^ (row & 7)) * 8;
                gload_lds16(A  + (size_t)(m0 + row)*KDIM + k0 + cc, &As[(wv*256 + i*64)*8]);
                gload_lds16(Bt + (size_t)(n0 + row)*KDIM + k0 + cc, &Bs[(wv*256 + i*64)*8]);
            }
            __syncthreads();
#pragma unroll
            for (int kf = 0; kf < 2; ++kf) {
                bf16x8 af[4], bfr[4];
#pragma unroll
                for (int mt = 0; mt < 4; ++mt)
                    af[mt] = *(const bf16x8*)&As[(wm + mt*16 + lm)*BK + (((kf<<2)|quad) ^ sw)*8];
#pragma unroll
                for (int nt = 0; nt < 4; ++nt)
                    bfr[nt] = *(const bf16x8*)&Bs[(wn + nt*16 + lm)*BK + (((kf<<2)|quad) ^ sw)*8];
#pragma unroll
                for (int mt = 0; mt < 4; ++mt)
#pragma unroll
                    for (int nt = 0; nt < 4; ++nt)
                        acc[mt][nt] = __builtin_amdgcn_mfma_f32_16x16x32_bf16(af[mt], bfr[nt], acc[mt][nt], 0, 0, 0);
            }
        }
#pragma unroll
        for (int mt = 0; mt < 4; ++mt) {
            int s4 = m0 + wm + mt*16 + quad*4;
            int b   = s4 >> 11;
            int kvt = (s4 & 2047) >> 6;
            int kv  = s4 & 63;
            int kf  = kv >> 5;
            int qv  = (kv >> 3) & 3;
            int j0  = kv & 7;
#pragma unroll
            for (int nt = 0; nt < 4; ++nt) {
                int cv = n0 + wn + nt*16 + lm - 2048;
                int h = cv >> 6, dv = cv & 63, nb = dv >> 4;
                float bs = bv[cv];
                bf16x4 pk;
#pragma unroll
                for (int r = 0; r < 4; ++r) pk[r] = (__bf16)(acc[mt][nt][r] + bs);
                size_t blk = (((size_t)((b*16 + h)*32 + kvt)*4 + nb)*2 + kf);
                *(bf16x4*)&vF[blk*512 + (qv*16 + lm)*8 + j0] = pk;
            }
        }
    }
}

// ---------------------------------------------------------------- flash attention v11
// ONE WAVE PER BLOCK (64 thr): 4096 independent fine-grained blocks -> near-perfect causal
// load balance + higher resident-wave occupancy (r12 was 23%, coarse 256-thr granularity).
// Per-wave compute is bit-identical to r12: barrier-free direct-frag loads + K-prefetch
// software pipeline + no-max exp2 softmax + ones-MFMA l. LDS = 2KB (per-wave P only).
// Mapping: bh = blockIdx.x>>7 (consecutive blocks share bh -> K/V L2 locality),
//          qt16 = 127 - (blockIdx.x&127) (heavy q-tiles dispatch first).

__global__ __launch_bounds__(64, 4) void attn_kernel(const __bf16* __restrict__ qF,
                                                     const __bf16* __restrict__ kF,
                                                     const __bf16* __restrict__ vF,
                                                     float* __restrict__ out) {
    const int bh = (int)blockIdx.x >> 7;
    const int b = bh >> 4, h = bh & 15;
    const int qt16 = 127 - ((int)blockIdx.x & 127);  // 16-row q-tile index, heavy first
    const int ln = threadIdx.x;
    const int quad = ln >> 4, lm = ln & 15;
    const int q0w = qt16 * 16;                      // this wave's 16 q-rows
    const int qg = q0w + lm;                        // this lane's q row

    __shared__ alignas(16) __bf16 Ps[16*64];        // per-wave P^T [q][kv], chunk-swizzled

    const int sw = lm & 7;                          // P swizzle key
    const __bf16* Kbase = kF + (((size_t)b*128*16 + h)*2)*512 + (size_t)ln*8;
    const __bf16* Vbase = vF + (((size_t)bh*32*4)*2)*512 + (size_t)ln*8;

    // Q fragments, pre-scaled by 0.125*log2(e) so P = exp2(S)
    const float qscale = 0.125f * 1.44269504088896f;
    bf16x8 qf[2];
#pragma unroll
    for (int kf = 0; kf < 2; ++kf) {
        bf16x8 t = *(const bf16x8*)&qF[((((size_t)b*128 + qt16)*16 + h)*2 + kf)*512 + ln*8];
#pragma unroll
        for (int j = 0; j < 8; ++j) t[j] = (__bf16)((float)t[j] * qscale);
        qf[kf] = t;
    }
    bf16x8 ones;
#pragma unroll
    for (int j = 0; j < 8; ++j) ones[j] = (__bf16)1.0f;

    f32x4 o[4] = {};                                // O^T: (dv = nb*16+quad*4+r, q = lm)
    f32x4 o5 = {};                                  // l accumulator: every reg = l(q=lm)
    const int nsteps = qt16/4 + 1;                  // KV 64-tiles covering [0, q0w+16)

    // ---- pipeline prologue: kfrag for step 0
    bf16x8 kcur[4][2], knxt[4][2];
#pragma unroll
    for (int nt = 0; nt < 4; ++nt)
#pragma unroll
        for (int kf = 0; kf < 2; ++kf)
            kcur[nt][kf] = *(const bf16x8*)(Kbase + (((size_t)nt*16)*2 + kf)*512);

    for (int st = 0; st < nsteps; ++st) {
        const int kv0 = st * 64;

        // ---- issue this step's V loads + next step's K prefetch (oldest-first)
        bf16x8 vfrag[4][2];
#pragma unroll
        for (int nb = 0; nb < 4; ++nb)
#pragma unroll
            for (int kf = 0; kf < 2; ++kf)
                vfrag[nb][kf] = *(const bf16x8*)(Vbase + (((size_t)st*4 + nb)*2 + kf)*512);
        if (st + 1 < nsteps) {
#pragma unroll
            for (int nt = 0; nt < 4; ++nt)
#pragma unroll
                for (int kf = 0; kf < 2; ++kf)
                    knxt[nt][kf] = *(const bf16x8*)(Kbase + (((size_t)((st+1)*4 + nt)*16)*2 + kf)*512);
        }

        // ---- S^T = K Q^T  (kcur resident since previous step)
        f32x4 s[4] = {};
#pragma unroll
        for (int nt = 0; nt < 4; ++nt)
#pragma unroll
            for (int kf = 0; kf < 2; ++kf)
                s[nt] = __builtin_amdgcn_mfma_f32_16x16x32_bf16(kcur[nt][kf], qf[kf], s[nt], 0, 0, 0);

        // ---- causal mask (diagonal step only; exp2(-1e9)=0)
        if (kv0 + 63 > q0w) {
#pragma unroll
            for (int nt = 0; nt < 4; ++nt)
#pragma unroll
                for (int r = 0; r < 4; ++r) {
                    int kvg = kv0 + nt*16 + quad*4 + r;
                    if (kvg > qg) s[nt][r] = -1e9f;
                }
        }

        // ---- P = exp2(s) -> per-wave LDS (swizzled 8B stores)
#pragma unroll
        for (int nt = 0; nt < 4; ++nt) {
            bf16x4 pb;
#pragma unroll
            for (int r = 0; r < 4; ++r)
                pb[r] = (__bf16)exp2f(s[nt][r]);
            int pos = ((nt*2 + (quad >> 1)) ^ sw);
            *(bf16x4*)&Ps[lm*64 + pos*8 + (quad & 1)*4] = pb;
        }

        // ---- O^T += V^T P^T ; l += 1^T P^T  (wave-local LDS RAW)
        bf16x8 pf0 = *(const bf16x8*)&Ps[lm*64 + ((0*4 + quad) ^ sw)*8];
        bf16x8 pf1 = *(const bf16x8*)&Ps[lm*64 + ((1*4 + quad) ^ sw)*8];
#pragma unroll
        for (int nb = 0; nb < 4; ++nb) {
            o[nb] = __builtin_amdgcn_mfma_f32_16x16x32_bf16(vfrag[nb][0], pf0, o[nb], 0, 0, 0);
            o[nb] = __builtin_amdgcn_mfma_f32_16x16x32_bf16(vfrag[nb][1], pf1, o[nb], 0, 0, 0);
        }
        o5 = __builtin_amdgcn_mfma_f32_16x16x32_bf16(ones, pf0, o5, 0, 0, 0);
        o5 = __builtin_amdgcn_mfma_f32_16x16x32_bf16(ones, pf1, o5, 0, 0, 0);

        // ---- rotate pipeline registers
#pragma unroll
        for (int nt = 0; nt < 4; ++nt)
#pragma unroll
            for (int kf = 0; kf < 2; ++kf)
                kcur[nt][kf] = knxt[nt][kf];
    }

    // ---- epilogue: every lane holds l(q=lm) in o5
    const float invl = 1.0f / o5[0];
    float* orow = out + (size_t)(b*SEQ + q0w + lm)*DIM + h*64;
#pragma unroll
    for (int nb = 0; nb < 4; ++nb) {
        float4 vres;
        vres.x = o[nb][0] * invl;
        vres.y = o[nb][1] * invl;
        vres.z = o[nb][2] * invl;
        vres.w = o[nb][3] * invl;
        *(float4*)&orow[nb*16 + quad*4] = vres;
    }
}

// ---------------------------------------------------------------- launcher
extern "C" void kernel_launch(void* const* d_in, const int* in_sizes, int n_in,
                              void* d_out, int out_size, void* d_ws, size_t ws_size,
                              hipStream_t stream) {
    const float* x   = (const float*)d_in[0];
    const float* Wqk = (const float*)d_in[1];
    const float* bqk = (const float*)d_in[2];
    const float* Wv  = (const float*)d_in[3];
    const float* bv  = (const float*)d_in[4];
    float* out = (float*)d_out;

    char* ws = (char*)d_ws;
    const size_t SZ_XB = (size_t)MROWS*KDIM*2;    // 8 MB
    const size_t SZ_WT = (size_t)NTOT*KDIM*2;     // 6 MB
    const size_t SZ_F  = (size_t)MROWS*1024*2;    // 8 MB per frag buffer
    __bf16* xb = (__bf16*)(ws);
    __bf16* Wt = (__bf16*)(ws + SZ_XB);
    __bf16* qF = (__bf16*)(ws + SZ_XB + SZ_WT);
    __bf16* kF = (__bf16*)(ws + SZ_XB + SZ_WT + SZ_F);
    __bf16* vF = (__bf16*)(ws + SZ_XB + SZ_WT + 2*SZ_F);

    prep_kernel    <<<4096 + 768, 256, 0, stream>>>(x, Wqk, Wv, xb, Wt);
    gemm_qkv_kernel<<<dim3(NTOT/BN, MROWS/BM), 256, 0, stream>>>(xb, Wt, bqk, bv, qF, kF, vF);
    attn_kernel    <<<4096, 64, 0, stream>>>(qF, kF, vF, out);
}

// Round 14
// 151.432 us; speedup vs baseline: 1.2638x; 1.2638x over previous
//
#include <hip/hip_runtime.h>
#include <hip/hip_bf16.h>
#include <math.h>

// Problem constants
#define BATCH 2
#define SEQ   2048
#define DIM   1024
#define HEADS 16
#define DH    64
#define MROWS (BATCH*SEQ)      // 4096
#define NTOT  3072             // gemm output cols: q(1024) | k(1024) | v(1024)
#define KDIM  1024

typedef float f32x4 __attribute__((ext_vector_type(4)));
typedef __bf16 bf16x8 __attribute__((ext_vector_type(8)));
typedef __bf16 bf16x4 __attribute__((ext_vector_type(4)));

// Fragment-order buffers (1KB block = 64 lanes x 16B chunk, lane ln = featquad*16 + (token&15)):
//  qF/kF: block index ((b*128 + g)*16 + h)*2 + kf      g = token-group (16 tokens)
//  vF   : block index ((bh*32 + kvt)*4 + nb)*2 + kf    kvt = kv/64, dv-group nb
// One 1KB block == one wave64 global_load_lds (base + ln*16B) == one b128 LDS frag read.

__device__ __forceinline__ void gload_lds16(const void* g, void* l) {
    __builtin_amdgcn_global_load_lds((__attribute__((address_space(1))) void*)g,
                                     (__attribute__((address_space(3))) void*)l,
                                     16, 0, 0);
}

// ---------------------------------------------- prep: cast x -> bf16  +  transpose W -> Wt
__global__ void prep_kernel(const float* __restrict__ x,
                            const float* __restrict__ Wqk, const float* __restrict__ Wv,
                            __bf16* __restrict__ xb, __bf16* __restrict__ Wt) {
    __shared__ float T[64*65];
    const int bx = blockIdx.x;
    const int tid = threadIdx.x;
    if (bx < 4096) {
        int i = bx * 256 + tid;                   // 1M float4 = 4M floats exactly
        float4 f = ((const float4*)x)[i];
        bf16x4 o;
        o.x = (__bf16)f.x; o.y = (__bf16)f.y; o.z = (__bf16)f.z; o.w = (__bf16)f.w;
        ((bf16x4*)xb)[i] = o;
    } else {
        const int t = bx - 4096;                  // 0..767
        const int n0 = (t % 48) * 64;
        const int k0 = (t / 48) * 64;
#pragma unroll
        for (int i = 0; i < 16; ++i) {
            int idx = i*256 + tid;
            int kk = idx >> 6, nn = idx & 63;
            int n = n0 + nn;
            float v = (n < 2048) ? Wqk[(size_t)(k0+kk)*2048 + n]
                                 : Wv [(size_t)(k0+kk)*1024 + (n - 2048)];
            T[kk*65 + nn] = v;
        }
        __syncthreads();
#pragma unroll
        for (int i = 0; i < 16; ++i) {
            int idx = i*256 + tid;
            int nn = idx >> 6, kk = idx & 63;
            Wt[(size_t)(n0+nn)*KDIM + k0 + kk] = (__bf16)T[kk*65 + nn];
        }
    }
}

// ---------------------------------------------------------------- GEMM v6 (r11, unchanged)
#define BM 128
#define BN 128
#define BK 64

__global__ __launch_bounds__(256) void gemm_qkv_kernel(const __bf16* __restrict__ A,
                                                       const __bf16* __restrict__ Bt,
                                                       const float* __restrict__ bqk,
                                                       const float* __restrict__ bv,
                                                       __bf16* __restrict__ qF,
                                                       __bf16* __restrict__ kF,
                                                       __bf16* __restrict__ vF) {
    __shared__ alignas(16) __bf16 As[BM*BK];
    __shared__ alignas(16) __bf16 Bs[BN*BK];
    const int tid = threadIdx.x;
    const int wv = tid >> 6, ln = tid & 63;
    const int quad = ln >> 4, lm = ln & 15;
    const int m0 = blockIdx.y * BM, n0 = blockIdx.x * BN;
    const int wm = (wv >> 1) * 64, wn = (wv & 1) * 64;
    const int sw = lm & 7;

    f32x4 acc[4][4] = {};

    if (n0 < 2048) {
        // ---------------- q/k path: acc[nt][mt] = C^T tiles ----------------
        for (int kt = 0; kt < KDIM/BK; ++kt) {
            const int k0 = kt * BK;
            __syncthreads();
#pragma unroll
            for (int i = 0; i < 4; ++i) {
                int slot = wv*256 + i*64 + ln;
                int row = slot >> 3, p = slot & 7;
                int cc = (p ^ (row & 7)) * 8;
                gload_lds16(A  + (size_t)(m0 + row)*KDIM + k0 + cc, &As[(wv*256 + i*64)*8]);
                gload_lds16(Bt + (size_t)(n0 + row)*KDIM + k0 + cc, &Bs[(wv*256 + i*64)*8]);
            }
            __syncthreads();
#pragma unroll
            for (int kf = 0; kf < 2; ++kf) {
                bf16x8 af[4], bfr[4];
#pragma unroll
                for (int mt = 0; mt < 4; ++mt)
                    af[mt] = *(const bf16x8*)&As[(wm + mt*16 + lm)*BK + (((kf<<2)|quad) ^ sw)*8];
#pragma unroll
                for (int nt = 0; nt < 4; ++nt)
                    bfr[nt] = *(const bf16x8*)&Bs[(wn + nt*16 + lm)*BK + (((kf<<2)|quad) ^ sw)*8];
#pragma unroll
                for (int nt = 0; nt < 4; ++nt)
#pragma unroll
                    for (int mt = 0; mt < 4; ++mt)
                        acc[nt][mt] = __builtin_amdgcn_mfma_f32_16x16x32_bf16(bfr[nt], af[mt], acc[nt][mt], 0, 0, 0);
            }
        }
        __bf16* dst = (n0 < 1024) ? qF : kF;        // block-uniform
#pragma unroll
        for (int nt = 0; nt < 4; ++nt) {
            int f = n0 + wn + nt*16 + quad*4;
            float4 bs4 = *(const float4*)&bqk[f];
            int fl = f & 1023;
            int h  = fl >> 6;
            int ff = fl & 63;
            int fquad = (ff >> 3) & 3;
            int j0 = ff & 7;
            int kf = ff >> 5;
#pragma unroll
            for (int mt = 0; mt < 4; ++mt) {
                int m = m0 + wm + mt*16 + lm;
                int b = m >> 11, g = (m & 2047) >> 4;
                bf16x4 pk;
                pk[0] = (__bf16)(acc[nt][mt][0] + bs4.x);
                pk[1] = (__bf16)(acc[nt][mt][1] + bs4.y);
                pk[2] = (__bf16)(acc[nt][mt][2] + bs4.z);
                pk[3] = (__bf16)(acc[nt][mt][3] + bs4.w);
                size_t blk = (((size_t)(b*128 + g)*16 + h)*2 + kf);
                *(bf16x4*)&dst[blk*512 + (fquad*16 + lm)*8 + j0] = pk;
            }
        }
    } else {
        // ---------------- v path: acc[mt][nt] = C tiles -> vF frag-order ----------------
        for (int kt = 0; kt < KDIM/BK; ++kt) {
            const int k0 = kt * BK;
            __syncthreads();
#pragma unroll
            for (int i = 0; i < 4; ++i) {
                int slot = wv*256 + i*64 + ln;
                int row = slot >> 3, p = slot & 7;
                int cc = (p ^ (row & 7)) * 8;
                gload_lds16(A  + (size_t)(m0 + row)*KDIM + k0 + cc, &As[(wv*256 + i*64)*8]);
                gload_lds16(Bt + (size_t)(n0 + row)*KDIM + k0 + cc, &Bs[(wv*256 + i*64)*8]);
            }
            __syncthreads();
#pragma unroll
            for (int kf = 0; kf < 2; ++kf) {
                bf16x8 af[4], bfr[4];
#pragma unroll
                for (int mt = 0; mt < 4; ++mt)
                    af[mt] = *(const bf16x8*)&As[(wm + mt*16 + lm)*BK + (((kf<<2)|quad) ^ sw)*8];
#pragma unroll
                for (int nt = 0; nt < 4; ++nt)
                    bfr[nt] = *(const bf16x8*)&Bs[(wn + nt*16 + lm)*BK + (((kf<<2)|quad) ^ sw)*8];
#pragma unroll
                for (int mt = 0; mt < 4; ++mt)
#pragma unroll
                    for (int nt = 0; nt < 4; ++nt)
                        acc[mt][nt] = __builtin_amdgcn_mfma_f32_16x16x32_bf16(af[mt], bfr[nt], acc[mt][nt], 0, 0, 0);
            }
        }
#pragma unroll
        for (int mt = 0; mt < 4; ++mt) {
            int s4 = m0 + wm + mt*16 + quad*4;
            int b   = s4 >> 11;
            int kvt = (s4 & 2047) >> 6;
            int kv  = s4 & 63;
            int kf  = kv >> 5;
            int qv  = (kv >> 3) & 3;
            int j0  = kv & 7;
#pragma unroll
            for (int nt = 0; nt < 4; ++nt) {
                int cv = n0 + wn + nt*16 + lm - 2048;
                int h = cv >> 6, dv = cv & 63, nb = dv >> 4;
                float bs = bv[cv];
                bf16x4 pk;
#pragma unroll
                for (int r = 0; r < 4; ++r) pk[r] = (__bf16)(acc[mt][nt][r] + bs);
                size_t blk = (((size_t)((b*16 + h)*32 + kvt)*4 + nb)*2 + kf);
                *(bf16x4*)&vF[blk*512 + (qv*16 + lm)*8 + j0] = pk;
            }
        }
    }
}

// ---------------------------------------------------------------- flash attention v12
// 4-wave blocks + frag-order K/V staged into SHARED LDS (L2 traffic /4 vs r11/r12 frag-direct,
// which was L2-BW-bound; r13's per-XCD refetch blowup reverted). Staging: ONE global_load_lds
// per 1KB frag block (wave-uniform dest + lane*16 IS the frag layout) - 16 insts/block-step.
// LDS frag reads are natural b128 at base+ln*16: conflict-free, no swizzle.
// Double-buffered; r12 math (exp2 + ones-MFMA l) -> bit-identical output.
// grid (32 bh, 32 qt heavy-first); LDS 40KB -> 4 blocks/CU.

__global__ __launch_bounds__(256, 4) void attn_kernel(const __bf16* __restrict__ qF,
                                                      const __bf16* __restrict__ kF,
                                                      const __bf16* __restrict__ vF,
                                                      float* __restrict__ out) {
    const int bh = blockIdx.x;
    const int b = bh >> 4, h = bh & 15;
    const int qt = 31 - (int)blockIdx.y;            // heavy blocks dispatched first
    const int qb = qt * 64;
    const int tid = threadIdx.x, wv = tid >> 6, ln = tid & 63;
    const int quad = ln >> 4, lm = ln & 15;
    const int q0w = qb + wv*16;                     // this wave's 16 q-rows
    const int qg = q0w + lm;                        // this lane's q row

    __shared__ alignas(16) __bf16 Ks[2][8*512];     // [buf][slot nt*2+kf][frag]
    __shared__ alignas(16) __bf16 Vs[2][8*512];     // [buf][slot nb*2+kf][frag]
    __shared__ alignas(16) __bf16 Ps[4][16*64];     // per-wave P^T [q][kv], chunk-swizzled

    const int sw = lm & 7;                          // P swizzle key

    // staging: wave wv stages 4 of the 16 frag blocks (wv 0,1 -> K slots, wv 2,3 -> V slots)
    auto issue = [&](int st, int buf) {
#pragma unroll
        for (int i = 0; i < 4; ++i) {
            int idx = wv*4 + i;                     // 0..15, wave-uniform branch below
            if (idx < 8) {
                int nt = idx >> 1, kf = idx & 1;
                const __bf16* g = kF + ((((size_t)b*128 + st*4 + nt)*16 + h)*2 + kf)*512 + (size_t)ln*8;
                gload_lds16(g, &Ks[buf][idx*512]);
            } else {
                int j = idx - 8;
                int nb = j >> 1, kf = j & 1;
                const __bf16* g = vF + ((((size_t)bh*32 + st)*4 + nb)*2 + kf)*512 + (size_t)ln*8;
                gload_lds16(g, &Vs[buf][j*512]);
            }
        }
    };

    // Q fragments, pre-scaled by 0.125*log2(e) so P = exp2(S)
    const float qscale = 0.125f * 1.44269504088896f;
    bf16x8 qf[2];
#pragma unroll
    for (int kf = 0; kf < 2; ++kf) {
        bf16x8 t = *(const bf16x8*)&qF[((((size_t)b*128 + (q0w >> 4))*16 + h)*2 + kf)*512 + ln*8];
#pragma unroll
        for (int j = 0; j < 8; ++j) t[j] = (__bf16)((float)t[j] * qscale);
        qf[kf] = t;
    }
    bf16x8 ones;
#pragma unroll
    for (int j = 0; j < 8; ++j) ones[j] = (__bf16)1.0f;

    f32x4 o[4] = {};                                // O^T: (dv = nb*16+quad*4+r, q = lm)
    f32x4 o5 = {};                                  // l accumulator: every reg = l(q=lm)
    const int nsteps = qt + 1;

    issue(0, 0);                                    // prologue prefetch
    for (int st = 0; st < nsteps; ++st) {
        const int cur = st & 1;
        const int kv0 = st * 64;
        __syncthreads();                            // drains buf[cur] loads; frees buf[cur^1]
        if (st + 1 < nsteps) issue(st + 1, cur ^ 1);// prefetch flies during this step's compute

        // ---- S^T = K Q^T : frag reads are natural b128, conflict-free
        f32x4 s[4] = {};
        bf16x8 kfrag[4][2];
#pragma unroll
        for (int nt = 0; nt < 4; ++nt)
#pragma unroll
            for (int kf = 0; kf < 2; ++kf)
                kfrag[nt][kf] = *(const bf16x8*)&Ks[cur][(nt*2 + kf)*512 + ln*8];
#pragma unroll
        for (int nt = 0; nt < 4; ++nt)
#pragma unroll
            for (int kf = 0; kf < 2; ++kf)
                s[nt] = __builtin_amdgcn_mfma_f32_16x16x32_bf16(kfrag[nt][kf], qf[kf], s[nt], 0, 0, 0);

        // ---- causal mask (diagonal step only; exp2(-1e9)=0)
        if (kv0 + 63 > q0w) {
#pragma unroll
            for (int nt = 0; nt < 4; ++nt)
#pragma unroll
                for (int r = 0; r < 4; ++r) {
                    int kvg = kv0 + nt*16 + quad*4 + r;
                    if (kvg > qg) s[nt][r] = -1e9f;
                }
        }

        // ---- P = exp2(s) -> per-wave LDS (swizzled 8B stores)
#pragma unroll
        for (int nt = 0; nt < 4; ++nt) {
            bf16x4 pb;
#pragma unroll
            for (int r = 0; r < 4; ++r)
                pb[r] = (__bf16)exp2f(s[nt][r]);
            int pos = ((nt*2 + (quad >> 1)) ^ sw);
            *(bf16x4*)&Ps[wv][lm*64 + pos*8 + (quad & 1)*4] = pb;
        }

        // ---- O^T += V^T P^T ; l += 1^T P^T  (wave-local LDS RAW)
        bf16x8 vfrag[4][2];
#pragma unroll
        for (int nb = 0; nb < 4; ++nb)
#pragma unroll
            for (int kf = 0; kf < 2; ++kf)
                vfrag[nb][kf] = *(const bf16x8*)&Vs[cur][(nb*2 + kf)*512 + ln*8];
        bf16x8 pf0 = *(const bf16x8*)&Ps[wv][lm*64 + ((0*4 + quad) ^ sw)*8];
        bf16x8 pf1 = *(const bf16x8*)&Ps[wv][lm*64 + ((1*4 + quad) ^ sw)*8];
#pragma unroll
        for (int nb = 0; nb < 4; ++nb) {
            o[nb] = __builtin_amdgcn_mfma_f32_16x16x32_bf16(vfrag[nb][0], pf0, o[nb], 0, 0, 0);
            o[nb] = __builtin_amdgcn_mfma_f32_16x16x32_bf16(vfrag[nb][1], pf1, o[nb], 0, 0, 0);
        }
        o5 = __builtin_amdgcn_mfma_f32_16x16x32_bf16(ones, pf0, o5, 0, 0, 0);
        o5 = __builtin_amdgcn_mfma_f32_16x16x32_bf16(ones, pf1, o5, 0, 0, 0);
    }

    // ---- epilogue: every lane holds l(q=lm) in o5
    const float invl = 1.0f / o5[0];
    float* orow = out + (size_t)(b*SEQ + q0w + lm)*DIM + h*64;
#pragma unroll
    for (int nb = 0; nb < 4; ++nb) {
        float4 vres;
        vres.x = o[nb][0] * invl;
        vres.y = o[nb][1] * invl;
        vres.z = o[nb][2] * invl;
        vres.w = o[nb][3] * invl;
        *(float4*)&orow[nb*16 + quad*4] = vres;
    }
}

// ---------------------------------------------------------------- launcher
extern "C" void kernel_launch(void* const* d_in, const int* in_sizes, int n_in,
                              void* d_out, int out_size, void* d_ws, size_t ws_size,
                              hipStream_t stream) {
    const float* x   = (const float*)d_in[0];
    const float* Wqk = (const float*)d_in[1];
    const float* bqk = (const float*)d_in[2];
    const float* Wv  = (const float*)d_in[3];
    const float* bv  = (const float*)d_in[4];
    float* out = (float*)d_out;

    char* ws = (char*)d_ws;
    const size_t SZ_XB = (size_t)MROWS*KDIM*2;    // 8 MB
    const size_t SZ_WT = (size_t)NTOT*KDIM*2;     // 6 MB
    const size_t SZ_F  = (size_t)MROWS*1024*2;    // 8 MB per frag buffer
    __bf16* xb = (__bf16*)(ws);
    __bf16* Wt = (__bf16*)(ws + SZ_XB);
    __bf16* qF = (__bf16*)(ws + SZ_XB + SZ_WT);
    __bf16* kF = (__bf16*)(ws + SZ_XB + SZ_WT + SZ_F);
    __bf16* vF = (__bf16*)(ws + SZ_XB + SZ_WT + 2*SZ_F);

    prep_kernel    <<<4096 + 768, 256, 0, stream>>>(x, Wqk, Wv, xb, Wt);
    gemm_qkv_kernel<<<dim3(NTOT/BN, MROWS/BM), 256, 0, stream>>>(xb, Wt, bqk, bv, qF, kF, vF);
    attn_kernel    <<<dim3(32, 32), 256, 0, stream>>>(qF, kF, vF, out);
}